// Round 1
// baseline (313.387 us; speedup 1.0000x reference)
//
#include <hip/hip_runtime.h>

#define NQ 8
#define BINS 256
#define D 128
#define ROWS_PER_BLOCK 16
#define THREADS 256
#define GROUPS 16            // threads cooperating on one row
#define BINS_PER_THREAD 16   // 256 / GROUPS
#define RSTRIDE 132          // 128 + 4 pad: conflict-free LDS rows

__global__ __launch_bounds__(THREADS) void rvq_kernel(
    const float* __restrict__ hidden,     // [N, D]
    const float* __restrict__ codebooks,  // [NQ, BINS, D]
    float* __restrict__ out_codes,        // [NQ, N] stored as float
    float* __restrict__ out_quant,        // [N, D]
    int N)
{
    __shared__ float res[ROWS_PER_BLOCK * RSTRIDE];
    __shared__ float red_dist[ROWS_PER_BLOCK][GROUPS];
    __shared__ int   red_idx[ROWS_PER_BLOCK][GROUPS];
    __shared__ int   win[ROWS_PER_BLOCK];

    const int t = threadIdx.x;
    const int row0 = blockIdx.x * ROWS_PER_BLOCK;

    // ---- load hidden rows into LDS residual (coalesced float4) ----
    #pragma unroll
    for (int i = 0; i < 2; ++i) {
        int f4 = t + i * THREADS;            // float4 index within block slab
        int r  = f4 >> 5;                    // 32 float4 per row
        int c4 = f4 & 31;
        float4 v = ((const float4*)hidden)[(size_t)(row0 + r) * 32 + c4];
        float* dst = &res[r * RSTRIDE + (c4 << 2)];
        dst[0] = v.x; dst[1] = v.y; dst[2] = v.z; dst[3] = v.w;
    }
    __syncthreads();

    const int row = t & (ROWS_PER_BLOCK - 1);
    const int g   = t >> 4;

    for (int level = 0; level < NQ; ++level) {
        const float* cb = codebooks + level * BINS * D;

        float best = INFINITY;
        int   bidx = 0;
        const float* rbase = &res[row * RSTRIDE];

        // 16 bins per thread, processed in pairs to reuse residual loads
        for (int bb = 0; bb < BINS_PER_THREAD; bb += 2) {
            int b0 = g * BINS_PER_THREAD + bb;
            const float4* c0 = (const float4*)(cb + b0 * D);
            const float4* c1 = (const float4*)(cb + (b0 + 1) * D);
            float4 acc0 = {0.f, 0.f, 0.f, 0.f};
            float4 acc1 = {0.f, 0.f, 0.f, 0.f};
            #pragma unroll 8
            for (int k = 0; k < 32; ++k) {
                float4 rr = *(const float4*)(rbase + (k << 2));
                float4 ca = c0[k];
                float4 cc = c1[k];
                float dx, dy, dz, dw;
                dx = rr.x - ca.x; dy = rr.y - ca.y; dz = rr.z - ca.z; dw = rr.w - ca.w;
                acc0.x += dx * dx; acc0.y += dy * dy; acc0.z += dz * dz; acc0.w += dw * dw;
                dx = rr.x - cc.x; dy = rr.y - cc.y; dz = rr.z - cc.z; dw = rr.w - cc.w;
                acc1.x += dx * dx; acc1.y += dy * dy; acc1.z += dz * dz; acc1.w += dw * dw;
            }
            float d0 = (acc0.x + acc0.y) + (acc0.z + acc0.w);
            float d1 = (acc1.x + acc1.y) + (acc1.z + acc1.w);
            // ascending scan with strict < keeps the lowest index on ties
            if (d0 < best) { best = d0; bidx = b0; }
            if (d1 < best) { best = d1; bidx = b0 + 1; }
        }
        red_dist[row][g] = best;
        red_idx[row][g]  = bidx;
        __syncthreads();

        // ---- per-row argmin reduce + code write (threads 0..15) ----
        if (t < ROWS_PER_BLOCK) {
            float bd = red_dist[t][0];
            int   bi = red_idx[t][0];
            #pragma unroll
            for (int j = 1; j < GROUPS; ++j) {
                float dj = red_dist[t][j];
                int   ij = red_idx[t][j];
                if (dj < bd || (dj == bd && ij < bi)) { bd = dj; bi = ij; }
            }
            win[t] = bi;
            out_codes[(size_t)level * N + row0 + t] = (float)bi;
        }
        __syncthreads();

        // ---- residual update: each thread owns 8 floats of its row ----
        {
            int w = win[row];
            const float* c = cb + w * D + g * 8;
            float* r = &res[row * RSTRIDE + g * 8];
            #pragma unroll
            for (int k = 0; k < 8; ++k) r[k] -= c[k];
        }
        __syncthreads();
    }

    // ---- epilogue: quantized = hidden - residual ----
    #pragma unroll
    for (int i = 0; i < 2; ++i) {
        int f4 = t + i * THREADS;
        int r  = f4 >> 5;
        int c4 = f4 & 31;
        float4 h = ((const float4*)hidden)[(size_t)(row0 + r) * 32 + c4];
        const float* rs = &res[r * RSTRIDE + (c4 << 2)];
        float4 q;
        q.x = h.x - rs[0]; q.y = h.y - rs[1]; q.z = h.z - rs[2]; q.w = h.w - rs[3];
        ((float4*)out_quant)[(size_t)(row0 + r) * 32 + c4] = q;
    }
}

extern "C" void kernel_launch(void* const* d_in, const int* in_sizes, int n_in,
                              void* d_out, int out_size, void* d_ws, size_t ws_size,
                              hipStream_t stream) {
    const float* hidden    = (const float*)d_in[0];
    const float* codebooks = (const float*)d_in[1];
    float* out = (float*)d_out;
    const int N = in_sizes[0] / D;                 // 8192
    float* out_codes = out;                        // [NQ, N]
    float* out_quant = out + (size_t)NQ * N;       // [N, D]
    dim3 grid(N / ROWS_PER_BLOCK);
    rvq_kernel<<<grid, THREADS, 0, stream>>>(hidden, codebooks, out_codes, out_quant, N);
}

// Round 2
// 182.118 us; speedup vs baseline: 1.7208x; 1.7208x over previous
//
#include <hip/hip_runtime.h>

#define NQ 8
#define BINS 256
#define D 128
#define RPB 16            // rows per block
#define THREADS 256
#define RGN 8             // row groups (t & 7), 2 rows each
#define BGN 32            // bin groups (t >> 3), 8 bins each
#define RSTRIDE 132       // 128 + 4 pad

__global__ __launch_bounds__(THREADS) void rvq_kernel(
    const float* __restrict__ hidden,     // [N, D]
    const float* __restrict__ codebooks,  // [NQ, BINS, D]
    float* __restrict__ out_codes,        // [NQ, N] stored as float
    float* __restrict__ out_quant,        // [N, D]
    int N)
{
    __shared__ float res[RPB * RSTRIDE];
    __shared__ unsigned long long red[RPB][BGN];
    __shared__ int win[RPB];

    const int t = threadIdx.x;
    const int row0 = blockIdx.x * RPB;

    // ---- load hidden rows into LDS residual (coalesced float4) ----
    #pragma unroll
    for (int i = 0; i < 2; ++i) {
        int f4 = t + i * THREADS;            // float4 index within block slab
        int r  = f4 >> 5;                    // 32 float4 per row
        int c4 = f4 & 31;
        float4 v = ((const float4*)hidden)[(size_t)(row0 + r) * 32 + c4];
        float* dst = &res[r * RSTRIDE + (c4 << 2)];
        dst[0] = v.x; dst[1] = v.y; dst[2] = v.z; dst[3] = v.w;
    }
    __syncthreads();

    const int rg = t & (RGN - 1);      // row group: rows {2rg, 2rg+1}
    const int bg = t >> 3;             // bin group: bins {8bg .. 8bg+7}
    const int r0 = rg * 2;

    for (int level = 0; level < NQ; ++level) {
        const float* cb  = codebooks + level * BINS * D;
        const float4* cbb = (const float4*)(cb + (bg * 8) * D); // 8-bin base; f4 idx j*32+kc

        float4 acc0[8], acc1[8];
        #pragma unroll
        for (int j = 0; j < 8; ++j) {
            acc0[j] = make_float4(0.f, 0.f, 0.f, 0.f);
            acc1[j] = make_float4(0.f, 0.f, 0.f, 0.f);
        }

        const float4* ra_base = (const float4*)&res[(r0    ) * RSTRIDE];
        const float4* rb_base = (const float4*)&res[(r0 + 1) * RSTRIDE];

        #pragma unroll 2
        for (int kc = 0; kc < 32; ++kc) {
            float4 ra = ra_base[kc];
            float4 rb = rb_base[kc];
            #pragma unroll
            for (int j = 0; j < 8; ++j) {
                float4 c = cbb[j * 32 + kc];   // offsets 0..4080B fit immediates
                float dx, dy, dz, dw;
                dx = ra.x - c.x; dy = ra.y - c.y; dz = ra.z - c.z; dw = ra.w - c.w;
                acc0[j].x += dx * dx; acc0[j].y += dy * dy;
                acc0[j].z += dz * dz; acc0[j].w += dw * dw;
                dx = rb.x - c.x; dy = rb.y - c.y; dz = rb.z - c.z; dw = rb.w - c.w;
                acc1[j].x += dx * dx; acc1[j].y += dy * dy;
                acc1[j].z += dz * dz; acc1[j].w += dw * dw;
            }
        }

        // per-thread best over its 8 bins, each row; ascending scan, strict <
        {
            float best0 = INFINITY, best1 = INFINITY;
            int   bi0 = 0, bi1 = 0;
            #pragma unroll
            for (int j = 0; j < 8; ++j) {
                int b = bg * 8 + j;
                float d0 = (acc0[j].x + acc0[j].y) + (acc0[j].z + acc0[j].w);
                float d1 = (acc1[j].x + acc1[j].y) + (acc1[j].z + acc1[j].w);
                if (d0 < best0) { best0 = d0; bi0 = b; }
                if (d1 < best1) { best1 = d1; bi1 = b; }
            }
            // pack (dist, idx): dist >= 0 so fp32 bit order == value order;
            // ties resolve to lowest index automatically
            red[r0    ][bg] = ((unsigned long long)__float_as_uint(best0) << 32) | (unsigned)bi0;
            red[r0 + 1][bg] = ((unsigned long long)__float_as_uint(best1) << 32) | (unsigned)bi1;
        }
        __syncthreads();

        // ---- per-row argmin reduce + code write (threads 0..15) ----
        if (t < RPB) {
            unsigned long long m = red[t][0];
            #pragma unroll
            for (int j = 1; j < BGN; ++j) {
                unsigned long long v = red[t][j];
                if (v < m) m = v;
            }
            int bi = (int)(m & 0xffffffffu);
            win[t] = bi;
            out_codes[(size_t)level * N + row0 + t] = (float)bi;
        }
        __syncthreads();

        // ---- residual update: row = t>>4, 8 floats per thread ----
        {
            int r = t >> 4;
            int g8 = t & 15;
            int w = win[r];
            const float* c = cb + w * D + g8 * 8;
            float* rp = &res[r * RSTRIDE + g8 * 8];
            #pragma unroll
            for (int k = 0; k < 8; ++k) rp[k] -= c[k];
        }
        __syncthreads();
    }

    // ---- epilogue: quantized = hidden - residual ----
    #pragma unroll
    for (int i = 0; i < 2; ++i) {
        int f4 = t + i * THREADS;
        int r  = f4 >> 5;
        int c4 = f4 & 31;
        float4 h = ((const float4*)hidden)[(size_t)(row0 + r) * 32 + c4];
        const float* rs = &res[r * RSTRIDE + (c4 << 2)];
        float4 q;
        q.x = h.x - rs[0]; q.y = h.y - rs[1]; q.z = h.z - rs[2]; q.w = h.w - rs[3];
        ((float4*)out_quant)[(size_t)(row0 + r) * 32 + c4] = q;
    }
}

extern "C" void kernel_launch(void* const* d_in, const int* in_sizes, int n_in,
                              void* d_out, int out_size, void* d_ws, size_t ws_size,
                              hipStream_t stream) {
    const float* hidden    = (const float*)d_in[0];
    const float* codebooks = (const float*)d_in[1];
    float* out = (float*)d_out;
    const int N = in_sizes[0] / D;                 // 8192
    float* out_codes = out;                        // [NQ, N]
    float* out_quant = out + (size_t)NQ * N;       // [N, D]
    dim3 grid(N / RPB);
    rvq_kernel<<<grid, THREADS, 0, stream>>>(hidden, codebooks, out_codes, out_quant, N);
}